// Round 6
// baseline (101.518 us; speedup 1.0000x reference)
//
#include <hip/hip_runtime.h>

typedef _Float16 half8 __attribute__((ext_vector_type(8)));
typedef _Float16 half2_t __attribute__((ext_vector_type(2)));
typedef float f32x4 __attribute__((ext_vector_type(4)));

#define OUT_Q 1ull
#define OUT_P 8388609ull
#define OUT_E 8388610ull
#define WS_LOSS 262144   // float offset of loss partials (after 512x512 u32 hist)

// Single fused kernel: stages codebook per-block, MFMA argmin, store-only tail.
// All global LOADS precede all global STORES; no mid-kernel vmcnt drains.
__global__ __launch_bounds__(512, 4)
void vq_main(const float* __restrict__ in, const float* __restrict__ emb,
             float* __restrict__ out, float* __restrict__ ws) {
    __shared__ __align__(16) unsigned int e16_lds[16384];  // 512 rows x 32 words, XOR-swizzled
    __shared__ float ebias_lds[512];
    __shared__ int idx_lds[256];
    __shared__ unsigned int hist_lds[512];

    const int tid  = threadIdx.x;
    const int lane = tid & 63;
    const int wid  = tid >> 6;              // 8 waves, 32 pixels each
    const int pb   = blockIdx.x * 256;      // block pixel base
    const int b    = pb >> 10;
    const int hw0  = pb & 1023;
    const int col  = lane & 15;             // MFMA col: pixel for A, code for C
    const int g    = lane >> 4;             // k-group

    hist_lds[tid] = 0u;

    // ---- input loads first (HBM latency hides under codebook staging)
    float xv[32];
    const float* xbase = in + (size_t)b * 65536 + hw0 + wid * 32;
#pragma unroll
    for (int i = 0; i < 2; ++i) {
        const float* xp = xbase + i * 16 + col;
#pragma unroll
        for (int ks = 0; ks < 2; ++ks)
#pragma unroll
            for (int e = 0; e < 8; ++e)
                xv[i * 16 + ks * 8 + e] = xp[(size_t)(ks * 32 + g * 8 + e) * 1024];
    }

    // ---- stage f32 codebook -> f16 LDS (word-XOR swizzle) + ebias via 16-lane reduce
    {
        const float4* emb4 = reinterpret_cast<const float4*>(emb);  // 8192 chunks
#pragma unroll
        for (int it = 0; it < 16; ++it) {
            const int u4i = it * 512 + tid;      // coalesced 8KB per iteration
            float4 v = emb4[u4i];
            const int r = u4i >> 4;              // code row
            const int c = u4i & 15;              // f32 chunk within row
            half2_t h0; h0.x = (_Float16)v.x; h0.y = (_Float16)v.y;
            half2_t h1; h1.x = (_Float16)v.z; h1.y = (_Float16)v.w;
            uint2 pk;
            pk.x = __builtin_bit_cast(unsigned int, h0);
            pk.y = __builtin_bit_cast(unsigned int, h1);
            *reinterpret_cast<uint2*>(&e16_lds[r * 32 + ((c * 2) ^ ((r & 7) << 2))]) = pk;
            float ps = v.x * v.x + v.y * v.y + v.z * v.z + v.w * v.w;
            ps += __shfl_xor(ps, 1, 64);
            ps += __shfl_xor(ps, 2, 64);
            ps += __shfl_xor(ps, 4, 64);
            ps += __shfl_xor(ps, 8, 64);
            if ((tid & 15) == 0) ebias_lds[r] = ps;
        }
    }

    // ---- A fragments (pre-scaled by -2) + |x|^2 partial
    half8 afrag[2][2];
    float sumsq = 0.0f;
#pragma unroll
    for (int i = 0; i < 2; ++i)
#pragma unroll
        for (int ks = 0; ks < 2; ++ks)
#pragma unroll
            for (int e = 0; e < 8; ++e) {
                float v = xv[i * 16 + ks * 8 + e];
                sumsq += v * v;
                afrag[i][ks][e] = (_Float16)(-2.0f * v);
            }

    __syncthreads();   // staging visible

    // ---- 32 code-tiles: acc init = |e|^2, B-frags from swizzled LDS
    float minv[2][4];
    int   mint[2][4];
#pragma unroll
    for (int i = 0; i < 2; ++i)
#pragma unroll
        for (int r = 0; r < 4; ++r) { minv[i][r] = __builtin_inff(); mint[i][r] = 0; }

    const int bswz = (col & 7) << 2;   // row&7 == col&7 for row = t*16+col
#pragma unroll 2
    for (int t = 0; t < 32; ++t) {
        const float bias = ebias_lds[(t << 4) + col];
        half8 bfrag[2];
#pragma unroll
        for (int ks = 0; ks < 2; ++ks)
            bfrag[ks] = *reinterpret_cast<const half8*>(
                &e16_lds[t * 512 + col * 32 + ((ks * 16 + g * 4) ^ bswz)]);
#pragma unroll
        for (int i = 0; i < 2; ++i) {
            f32x4 acc = { bias, bias, bias, bias };
            acc = __builtin_amdgcn_mfma_f32_16x16x32_f16(afrag[i][0], bfrag[0], acc, 0, 0, 0);
            acc = __builtin_amdgcn_mfma_f32_16x16x32_f16(afrag[i][1], bfrag[1], acc, 0, 0, 0);
#pragma unroll
            for (int r = 0; r < 4; ++r) {
                if (acc[r] < minv[i][r]) { minv[i][r] = acc[r]; mint[i][r] = t; }
            }
        }
    }

    // ---- cross-lane argmin over the 16 code-columns (pixel = g*4+r of ptile i)
    float vsum = 0.0f;
#pragma unroll
    for (int i = 0; i < 2; ++i) {
#pragma unroll
        for (int r = 0; r < 4; ++r) {
            float v = minv[i][r];
            int   k = (mint[i][r] << 4) + col;
#pragma unroll
            for (int off = 1; off < 16; off <<= 1) {
                float v2 = __shfl_xor(v, off, 64);
                int   k2 = __shfl_xor(k, off, 64);
                if (v2 < v || (v2 == v && k2 < k)) { v = v2; k = k2; }
            }
            if (col == 0) {
                idx_lds[wid * 32 + i * 16 + g * 4 + r] = k;
                vsum += v;
            }
        }
    }

    // per-wave loss partial (stored after the last barrier)
    float lossp = vsum + sumsq;
#pragma unroll
    for (int off = 32; off > 0; off >>= 1) lossp += __shfl_down(lossp, off, 64);

    __syncthreads();   // idx_lds visible

    if (tid < 256) atomicAdd(&hist_lds[idx_lds[tid]], 1u);

    __syncthreads();   // hist complete

    // ================= store-only phase: no loads below, no barriers below ====

    if (lane == 0) ws[WS_LOSS + blockIdx.x * 8 + wid] = lossp;
    reinterpret_cast<unsigned int*>(ws)[blockIdx.x * 512 + tid] = hist_lds[tid];

    // ---- quantized NCHW from LDS f16 rows (exact cvt), pixel-coalesced stores
    {
        const int p   = tid & 255;
        const int ch0 = (tid >> 8) * 32;
        const int R   = idx_lds[p];
        const int qswz = (R & 7) << 2;
        float* q = out + OUT_Q + (size_t)b * 65536 + hw0 + p;
#pragma unroll
        for (int j = 0; j < 4; ++j) {
            uint4 u = *reinterpret_cast<const uint4*>(
                &e16_lds[R * 32 + (((ch0 >> 1) + j * 4) ^ qswz)]);
            const int c = ch0 + j * 8;
            half2_t h0 = __builtin_bit_cast(half2_t, u.x);
            half2_t h1 = __builtin_bit_cast(half2_t, u.y);
            half2_t h2 = __builtin_bit_cast(half2_t, u.z);
            half2_t h3 = __builtin_bit_cast(half2_t, u.w);
            q[(size_t)(c + 0) * 1024] = (float)h0.x;
            q[(size_t)(c + 1) * 1024] = (float)h0.y;
            q[(size_t)(c + 2) * 1024] = (float)h1.x;
            q[(size_t)(c + 3) * 1024] = (float)h1.y;
            q[(size_t)(c + 4) * 1024] = (float)h2.x;
            q[(size_t)(c + 5) * 1024] = (float)h2.y;
            q[(size_t)(c + 6) * 1024] = (float)h3.x;
            q[(size_t)(c + 7) * 1024] = (float)h3.y;
        }
    }

    // ---- one-hot rows: region base is ==8 mod 16, so cols 2..509 are 127
    // aligned uint4 slots + two uint2 edges. 128 threads/row, 4 rows/iter.
    {
        const int k  = tid & 127;
        const int rq = tid >> 7;
        const int c0 = 2 + k * 4;
        for (int rr = 0; rr < 64; ++rr) {
            const int row = rr * 4 + rq;
            const int idx = idx_lds[row];
            float* encRow = out + OUT_E + (size_t)(pb + row) * 512;
            if (k < 127) {
                uint4 v;
                v.x = (c0     == idx) ? 0x3f800000u : 0u;
                v.y = (c0 + 1 == idx) ? 0x3f800000u : 0u;
                v.z = (c0 + 2 == idx) ? 0x3f800000u : 0u;
                v.w = (c0 + 3 == idx) ? 0x3f800000u : 0u;
                *reinterpret_cast<uint4*>(
                    __builtin_assume_aligned(encRow + c0, 16)) = v;
            } else {
                uint2 a, z;
                a.x = (0   == idx) ? 0x3f800000u : 0u;
                a.y = (1   == idx) ? 0x3f800000u : 0u;
                z.x = (510 == idx) ? 0x3f800000u : 0u;
                z.y = (511 == idx) ? 0x3f800000u : 0u;
                *reinterpret_cast<uint2*>(encRow)       = a;
                *reinterpret_cast<uint2*>(encRow + 510) = z;
            }
        }
    }
}

__global__ __launch_bounds__(512)
void vq_finalize(const float* __restrict__ ws, float* __restrict__ out) {
    __shared__ float red[512];
    const int t = threadIdx.x;
    if (blockIdx.x == 0) {
        // perplexity from per-block histograms
        const unsigned int* h = reinterpret_cast<const unsigned int*>(ws);
        unsigned int s = 0;
#pragma unroll 8
        for (int bb = 0; bb < 512; ++bb) s += h[bb * 512 + t];
        float p = (float)s * (1.0f / 131072.0f);
        red[t] = p * logf(p + 1e-10f);
        for (int off = 256; off > 0; off >>= 1) {
            __syncthreads();
            if (t < off) red[t] += red[t + off];
        }
        if (t == 0) out[OUT_P] = expf(-red[0]);
    } else {
        // loss from per-wave partials
        const float* lp = ws + WS_LOSS;
        float l = 0.0f;
#pragma unroll
        for (int j = 0; j < 8; ++j) l += lp[t + 512 * j];
        red[t] = l;
        for (int off = 256; off > 0; off >>= 1) {
            __syncthreads();
            if (t < off) red[t] += red[t + off];
        }
        if (t == 0) out[0] = 1.25f * red[0] / 8388608.0f;  // (1+0.25)*mean dist
    }
}

extern "C" void kernel_launch(void* const* d_in, const int* in_sizes, int n_in,
                              void* d_out, int out_size, void* d_ws, size_t ws_size,
                              hipStream_t stream) {
    (void)in_sizes; (void)n_in; (void)out_size; (void)ws_size;
    const float* in  = (const float*)d_in[0];
    const float* emb = (const float*)d_in[1];
    float* out = (float*)d_out;
    float* ws  = (float*)d_ws;

    vq_main<<<dim3(512), dim3(512), 0, stream>>>(in, emb, out, ws);
    vq_finalize<<<dim3(2), dim3(512), 0, stream>>>(ws, out);
}